// Round 14
// baseline (133.082 us; speedup 1.0000x reference)
//
#include <hip/hip_runtime.h>
#include <hip/hip_cooperative_groups.h>
#include <stdint.h>

namespace cg = cooperative_groups;

// Tropical (max-plus) matmul: Y[b][j] = max_k X[b][k] + W[j][k]
// M=512, N=1024, K=1024, fp32 in/out.
//
// Exact candidate pruning (R11 theorem): with D >= max_j spread_j
// (spread_j = max_k W[j,k] - min_k W[j,k]), any k with X[b,k] <= Xmax_b - D
// loses to k* = argmax X[b,:] for every j. |C_b| ~ 1-3 (W = randn*0.02).
// Exact fp32; CAP overflow -> coalesced full-scan fallback.
//
// R13 post-mortem: 2-dispatch version left ~22us of kernel time; biggest
// identified item was K2's per-block 128KB D-reduce (64MB cross-XCD L3).
// R14: ONE cooperative dispatch, 256 blocks x 256 thr (1 block/CU,
// co-resident). Phase A: tile transpose + pmax/pmin partials. sync.
// Phase B: each block reduces 4 j's -> Dpart[256]. sync. Phase C: blocks
// read 1KB of Dparts -> D, then 2 b-rows each: Xmax, candidates, emit.

#define M_DIM 512
#define N_DIM 1024
#define K_DIM 1024
#define CAP 128

// ws layout: Wt 4MB | pmax 64KB | pmin 64KB | Dpart 1KB
#define OFF_WT    0
#define OFF_PMAX  (4u * 1024u * 1024u)
#define OFF_PMIN  (OFF_PMAX + 64u * 1024u)
#define OFF_DPART (OFF_PMIN + 64u * 1024u)

__global__ __launch_bounds__(256)
void tropical_fused(const float* __restrict__ X, const float* __restrict__ W,
                    float* __restrict__ out, float* __restrict__ Wt,
                    float* __restrict__ pmax, float* __restrict__ pmin,
                    float* __restrict__ Dpart) {
    __shared__ float L[64][65];       // transpose tile (+1 pad)
    __shared__ float smx[4][64];
    __shared__ float smn[4][64];
    __shared__ float red[256];
    __shared__ float sval[CAP];
    __shared__ int sidx[CAP];
    __shared__ int scnt;

    cg::grid_group grid = cg::this_grid();

    const int tid = threadIdx.x;
    const int bx = blockIdx.x;        // 0..255
    const int kt = bx & 15;
    const int jt = bx >> 4;
    const int k0 = kt * 64, j0 = jt * 64;

    // ================= Phase A: transpose tile + spread partials ==========
    {   // load 64j x 64k: j-row r, 16 k's per thread
        const int r = tid >> 2, q = tid & 3;
        const float* g = &W[(size_t)(j0 + r) * K_DIM + k0 + q * 16];
#pragma unroll
        for (int t = 0; t < 4; t++) {
            float4 f = *(const float4*)(g + 4 * t);
            L[r][q * 16 + 4 * t + 0] = f.x;
            L[r][q * 16 + 4 * t + 1] = f.y;
            L[r][q * 16 + 4 * t + 2] = f.z;
            L[r][q * 16 + 4 * t + 3] = f.w;
        }
    }
    __syncthreads();
    {   // write Wt tile: k-row kk, 16 j's per thread
        const int kk = tid >> 2, q = tid & 3;
        float* o = &Wt[(size_t)(k0 + kk) * N_DIM + j0 + q * 16];
#pragma unroll
        for (int t = 0; t < 4; t++) {
            float4 f = {L[q * 16 + 4 * t + 0][kk], L[q * 16 + 4 * t + 1][kk],
                        L[q * 16 + 4 * t + 2][kk], L[q * 16 + 4 * t + 3][kk]};
            *(float4*)(o + 4 * t) = f;
        }
    }
    {   // per-j min/max over this tile's 64 k's (4 threads per j)
        const int jl = tid & 63, seg = tid >> 6;
        float mx = -3.0e38f, mn = 3.0e38f;
#pragma unroll
        for (int i = 0; i < 16; i++) {
            float v = L[jl][seg * 16 + i];
            mx = fmaxf(mx, v);
            mn = fminf(mn, v);
        }
        smx[seg][jl] = mx;
        smn[seg][jl] = mn;
    }
    __syncthreads();
    if (tid < 64) {
        float mx = fmaxf(fmaxf(smx[0][tid], smx[1][tid]), fmaxf(smx[2][tid], smx[3][tid]));
        float mn = fminf(fminf(smn[0][tid], smn[1][tid]), fminf(smn[2][tid], smn[3][tid]));
        pmax[kt * N_DIM + j0 + tid] = mx;
        pmin[kt * N_DIM + j0 + tid] = mn;
    }

    grid.sync();

    // ================= Phase B: block bx reduces j = bx*4 .. +3 ===========
    {
        // 64 threads: j_loc = tid>>4 (0..3), ktt = tid&15
        if (tid < 64) {
            const int j = bx * 4 + (tid >> 4);
            const int ktt = tid & 15;
            smx[0][tid] = pmax[ktt * N_DIM + j];
            smn[0][tid] = pmin[ktt * N_DIM + j];
        }
        __syncthreads();
        if (tid < 4) {
            float mx = -3.0e38f, mn = 3.0e38f;
#pragma unroll
            for (int ktt = 0; ktt < 16; ktt++) {
                mx = fmaxf(mx, smx[0][tid * 16 + ktt]);
                mn = fminf(mn, smn[0][tid * 16 + ktt]);
            }
            red[tid] = mx - mn;   // spread_j
        }
        __syncthreads();
        if (tid == 0)
            Dpart[bx] = fmaxf(fmaxf(red[0], red[1]), fmaxf(red[2], red[3]));
    }

    grid.sync();

    // ================= Phase C: D, then 2 b-rows per block ================
    if (tid < 64) {
        float4 dp = ((const float4*)Dpart)[tid];
        red[tid] = fmaxf(fmaxf(dp.x, dp.y), fmaxf(dp.z, dp.w));
    }
    __syncthreads();
    for (int s = 32; s > 0; s >>= 1) {
        if (tid < s) red[tid] = fmaxf(red[tid], red[tid + s]);
        __syncthreads();
    }
    const float D = red[0] * 1.0001f + 1e-6f;   // pad vs fp rounding

#pragma unroll 1
    for (int rep = 0; rep < 2; rep++) {
        const int b = bx * 2 + rep;

        __syncthreads();   // protect red[]/scnt reuse across reps
        // Xmax_b
        const float4 xv = ((const float4*)X)[b * (K_DIM / 4) + tid];
        red[tid] = fmaxf(fmaxf(xv.x, xv.y), fmaxf(xv.z, xv.w));
        if (tid == 0) scnt = 0;
        __syncthreads();
        for (int s = 128; s > 0; s >>= 1) {
            if (tid < s) red[tid] = fmaxf(red[tid], red[tid + s]);
            __syncthreads();
        }
        const float thr = red[0] - D;

        // candidates
        const float xa[4] = {xv.x, xv.y, xv.z, xv.w};
#pragma unroll
        for (int c = 0; c < 4; c++) {
            if (xa[c] > thr) {
                int p = atomicAdd(&scnt, 1);
                if (p < CAP) { sidx[p] = tid * 4 + c; sval[p] = xa[c]; }
            }
        }
        __syncthreads();
        const int n = scnt;

        // emit: coalesced float4 reads of Wt rows
        float4 acc = {-3.0e38f, -3.0e38f, -3.0e38f, -3.0e38f};
        if (n <= CAP) {
            for (int c = 0; c < n; c++) {
                const int k = sidx[c];
                const float xk = sval[c];
                const float4 w = ((const float4*)Wt)[k * (N_DIM / 4) + tid];
                acc.x = fmaxf(acc.x, xk + w.x);
                acc.y = fmaxf(acc.y, xk + w.y);
                acc.z = fmaxf(acc.z, xk + w.z);
                acc.w = fmaxf(acc.w, xk + w.w);
            }
        } else {
            // overflow fallback (prob ~0): exact full scan
            for (int k = 0; k < K_DIM; k++) {
                const float xk = X[(size_t)b * K_DIM + k];
                const float4 w = ((const float4*)Wt)[k * (N_DIM / 4) + tid];
                acc.x = fmaxf(acc.x, xk + w.x);
                acc.y = fmaxf(acc.y, xk + w.y);
                acc.z = fmaxf(acc.z, xk + w.z);
                acc.w = fmaxf(acc.w, xk + w.w);
            }
        }
        ((float4*)out)[b * (N_DIM / 4) + tid] = acc;
    }
}

extern "C" void kernel_launch(void* const* d_in, const int* in_sizes, int n_in,
                              void* d_out, int out_size, void* d_ws, size_t ws_size,
                              hipStream_t stream) {
    const float* X = (const float*)d_in[0];   // [512][1024]
    const float* W = (const float*)d_in[1];   // [1024][1024]
    float* out = (float*)d_out;               // [512][1024]

    char* ws = (char*)d_ws;
    float* Wt    = (float*)(ws + OFF_WT);
    float* pmax  = (float*)(ws + OFF_PMAX);
    float* pmin  = (float*)(ws + OFF_PMIN);
    float* Dpart = (float*)(ws + OFF_DPART);

    void* args[] = {(void*)&X, (void*)&W, (void*)&out, (void*)&Wt,
                    (void*)&pmax, (void*)&pmin, (void*)&Dpart};
    hipLaunchCooperativeKernel((const void*)tropical_fused,
                               dim3(256), dim3(256), args, 0, stream);
}

// Round 15
// 64.222 us; speedup vs baseline: 2.0722x; 2.0722x over previous
//
#include <hip/hip_runtime.h>
#include <stdint.h>

// Tropical (max-plus) matmul: Y[b][j] = max_k X[b][k] + W[j][k]
// M=512, N=1024, K=1024, fp32 in/out.
//
// Exact candidate pruning: with any D >= max_j (max_k W[j,k] - min_k W[j,k]),
// k with X[b,k] <= Xmax_b - D loses to k* = argmax X[b,:] for every j.
// R15 uses the GLOBAL spread D'' = max(W) - min(W) >= max_j spread_j
// (still exact; D'' ~ 0.2 for W = randn*0.02 -> ~3 candidates/row).
// CAP overflow -> coalesced full-scan fallback keeps it exact always.
//
// R14 post-mortem: grid.sync() ~ 30us each on 256 blocks -> cooperative
// fusion is a dead end; dispatch boundaries (~2.6us) are the cheap barrier.
// R15 = R13's 2-dispatch shape, but per-block D-reduce reads 2 KB of tile
// min/max (plain stores from K1) instead of 128 KB of per-j partials
// (64 MB -> 1 MB chip-wide).

#define M_DIM 512
#define N_DIM 1024
#define K_DIM 1024
#define CAP 128

// ws layout: Wt 4MB | tmax 1KB | tmin 1KB
#define OFF_WT    0
#define OFF_TMAX  (4u * 1024u * 1024u)
#define OFF_TMIN  (OFF_TMAX + 1024u)

// ---- K1: transpose 64x64 tile + tile-global min/max (plain store) ----
__global__ __launch_bounds__(256)
void transpose_spread(const float* __restrict__ W, float* __restrict__ Wt,
                      float* __restrict__ tmax, float* __restrict__ tmin) {
    __shared__ float L[64][65];     // +1 pad
    __shared__ float smx[4][64];
    __shared__ float smn[4][64];

    const int tid = threadIdx.x;
    const int kt = blockIdx.x;      // 0..15
    const int jt = blockIdx.y;      // 0..15
    const int k0 = kt * 64, j0 = jt * 64;

    {   // load: j-row r, 16 k's per thread
        const int r = tid >> 2, q = tid & 3;
        const float* g = &W[(size_t)(j0 + r) * K_DIM + k0 + q * 16];
#pragma unroll
        for (int t = 0; t < 4; t++) {
            float4 f = *(const float4*)(g + 4 * t);
            L[r][q * 16 + 4 * t + 0] = f.x;
            L[r][q * 16 + 4 * t + 1] = f.y;
            L[r][q * 16 + 4 * t + 2] = f.z;
            L[r][q * 16 + 4 * t + 3] = f.w;
        }
    }
    __syncthreads();
    {   // write Wt tile: k-row kk, 16 j's per thread
        const int kk = tid >> 2, q = tid & 3;
        float* o = &Wt[(size_t)(k0 + kk) * N_DIM + j0 + q * 16];
#pragma unroll
        for (int t = 0; t < 4; t++) {
            float4 f = {L[q * 16 + 4 * t + 0][kk], L[q * 16 + 4 * t + 1][kk],
                        L[q * 16 + 4 * t + 2][kk], L[q * 16 + 4 * t + 3][kk]};
            *(float4*)(o + 4 * t) = f;
        }
    }
    {   // per-j partial min/max (4 threads per j), then tile-global reduce
        const int jl = tid & 63, seg = tid >> 6;
        float mx = -3.0e38f, mn = 3.0e38f;
#pragma unroll
        for (int i = 0; i < 16; i++) {
            float v = L[jl][seg * 16 + i];
            mx = fmaxf(mx, v);
            mn = fminf(mn, v);
        }
        smx[seg][jl] = mx;
        smn[seg][jl] = mn;
    }
    __syncthreads();
    if (tid < 64) {
        smx[0][tid] = fmaxf(fmaxf(smx[0][tid], smx[1][tid]), fmaxf(smx[2][tid], smx[3][tid]));
        smn[0][tid] = fminf(fminf(smn[0][tid], smn[1][tid]), fminf(smn[2][tid], smn[3][tid]));
    }
    __syncthreads();
    for (int s = 32; s > 0; s >>= 1) {
        if (tid < s) {
            smx[0][tid] = fmaxf(smx[0][tid], smx[0][tid + s]);
            smn[0][tid] = fminf(smn[0][tid], smn[0][tid + s]);
        }
        __syncthreads();
    }
    if (tid == 0) {
        const int id = jt * 16 + kt;
        tmax[id] = smx[0][0];
        tmin[id] = smn[0][0];
    }
}

// ---- K2: D from 2KB, Xmax, candidates, coalesced emit from Wt rows ----
__global__ __launch_bounds__(256)
void emit_pruned(const float* __restrict__ X, const float* __restrict__ Wt,
                 const float* __restrict__ tmax, const float* __restrict__ tmin,
                 float* __restrict__ out) {
    __shared__ float red[256];
    __shared__ float redmn[64];
    __shared__ float sval[CAP];
    __shared__ int sidx[CAP];
    __shared__ int scnt;

    const int tid = threadIdx.x;
    const int b = blockIdx.x;

    // --- D'' = max(W) - min(W) from 256 tile pairs (2 KB, coalesced) ---
    if (tid < 64) {
        float4 a = ((const float4*)tmax)[tid];
        float4 i = ((const float4*)tmin)[tid];
        red[tid]   = fmaxf(fmaxf(a.x, a.y), fmaxf(a.z, a.w));
        redmn[tid] = fminf(fminf(i.x, i.y), fminf(i.z, i.w));
    }
    if (tid == 0) scnt = 0;
    __syncthreads();
    for (int s = 32; s > 0; s >>= 1) {
        if (tid < s) {
            red[tid]   = fmaxf(red[tid], red[tid + s]);
            redmn[tid] = fminf(redmn[tid], redmn[tid + s]);
        }
        __syncthreads();
    }
    const float D = (red[0] - redmn[0]) * 1.0001f + 1e-6f;  // pad vs fp rounding
    __syncthreads();                                         // before red[] reuse

    // --- Xmax_b ---
    const float4 xv = ((const float4*)X)[b * (K_DIM / 4) + tid];
    red[tid] = fmaxf(fmaxf(xv.x, xv.y), fmaxf(xv.z, xv.w));
    __syncthreads();
    for (int s = 128; s > 0; s >>= 1) {
        if (tid < s) red[tid] = fmaxf(red[tid], red[tid + s]);
        __syncthreads();
    }
    const float thr = red[0] - D;

    // --- candidate list ---
    const float xa[4] = {xv.x, xv.y, xv.z, xv.w};
#pragma unroll
    for (int c = 0; c < 4; c++) {
        if (xa[c] > thr) {
            int p = atomicAdd(&scnt, 1);
            if (p < CAP) { sidx[p] = tid * 4 + c; sval[p] = xa[c]; }
        }
    }
    __syncthreads();
    const int n = scnt;

    // --- emit: coalesced float4 reads of Wt rows ---
    float4 acc = {-3.0e38f, -3.0e38f, -3.0e38f, -3.0e38f};
    if (n <= CAP) {
        for (int c = 0; c < n; c++) {
            const int k = sidx[c];
            const float xk = sval[c];
            const float4 w = ((const float4*)Wt)[k * (N_DIM / 4) + tid];
            acc.x = fmaxf(acc.x, xk + w.x);
            acc.y = fmaxf(acc.y, xk + w.y);
            acc.z = fmaxf(acc.z, xk + w.z);
            acc.w = fmaxf(acc.w, xk + w.w);
        }
    } else {
        // overflow fallback (prob ~0): exact full scan, still coalesced
        for (int k = 0; k < K_DIM; k++) {
            const float xk = X[(size_t)b * K_DIM + k];
            const float4 w = ((const float4*)Wt)[k * (N_DIM / 4) + tid];
            acc.x = fmaxf(acc.x, xk + w.x);
            acc.y = fmaxf(acc.y, xk + w.y);
            acc.z = fmaxf(acc.z, xk + w.z);
            acc.w = fmaxf(acc.w, xk + w.w);
        }
    }
    ((float4*)out)[b * (N_DIM / 4) + tid] = acc;
}

extern "C" void kernel_launch(void* const* d_in, const int* in_sizes, int n_in,
                              void* d_out, int out_size, void* d_ws, size_t ws_size,
                              hipStream_t stream) {
    const float* X = (const float*)d_in[0];   // [512][1024]
    const float* W = (const float*)d_in[1];   // [1024][1024]
    float* out = (float*)d_out;               // [512][1024]

    char* ws = (char*)d_ws;
    float* Wt   = (float*)(ws + OFF_WT);
    float* tmax = (float*)(ws + OFF_TMAX);
    float* tmin = (float*)(ws + OFF_TMIN);

    transpose_spread<<<dim3(16, 16), 256, 0, stream>>>(W, Wt, tmax, tmin);
    emit_pruned<<<M_DIM, 256, 0, stream>>>(X, Wt, tmax, tmin, out);
}

// Round 16
// 63.687 us; speedup vs baseline: 2.0896x; 1.0084x over previous
//
#include <hip/hip_runtime.h>
#include <stdint.h>

// Tropical (max-plus) matmul: Y[b][j] = max_k X[b][k] + W[j][k]
// M=512, N=1024, K=1024, fp32 in/out.
//
// Exact candidate pruning: with any D >= max_j (max_k W[j,k] - min_k W[j,k]),
// k with X[b,k] <= Xmax_b - D loses to k* = argmax X[b,:] for every j.
// Global spread D'' = max(W) - min(W) >= that bound (still exact; ~3
// candidates/row at W = randn*0.02). CAP overflow -> coalesced full-scan
// fallback keeps the kernel exact for ANY input.
//
// R16 (vs R15): K1 grid 768 = 256 transpose+tile-minmax blocks + 512 Xmax[b]
// blocks (wave-shuffle reduce); K2 loses its 8-barrier Xmax tree and its
// 6-barrier D tree (one 64-lane shuffle butterfly instead). 2 dispatches
// (R14 measured grid-wide coherence barriers at ~30us -> kernel boundary
// is the cheap global barrier on 8-XCD CDNA4).

#define M_DIM 512
#define N_DIM 1024
#define K_DIM 1024
#define CAP 128

// ws layout: Wt 4MB | tmax 1KB | tmin 1KB | Xmax 2KB
#define OFF_WT    0
#define OFF_TMAX  (4u * 1024u * 1024u)
#define OFF_TMIN  (OFF_TMAX + 1024u)
#define OFF_XMAX  (OFF_TMIN + 1024u)

// ---- K1: [0,256) transpose 64x64 W-tile + tile min/max; [256,768) Xmax[b] ----
__global__ __launch_bounds__(256)
void prep(const float* __restrict__ W, const float* __restrict__ X,
          float* __restrict__ Wt, float* __restrict__ tmax,
          float* __restrict__ tmin, float* __restrict__ Xmax) {
    __shared__ float L[64][65];     // +1 pad
    __shared__ float smx[4][64];
    __shared__ float smn[4][64];

    const int tid = threadIdx.x;
    const int bx = blockIdx.x;

    if (bx >= 256) {
        // ---- Xmax for row b ----
        const int b = bx - 256;
        const float4 xv = ((const float4*)X)[b * (K_DIM / 4) + tid];
        float m = fmaxf(fmaxf(xv.x, xv.y), fmaxf(xv.z, xv.w));
#pragma unroll
        for (int off = 32; off > 0; off >>= 1)
            m = fmaxf(m, __shfl_down(m, off, 64));
        if ((tid & 63) == 0) smx[0][tid >> 6] = m;
        __syncthreads();
        if (tid == 0)
            Xmax[b] = fmaxf(fmaxf(smx[0][0], smx[0][1]),
                            fmaxf(smx[0][2], smx[0][3]));
        return;
    }

    const int kt = bx & 15;
    const int jt = bx >> 4;
    const int k0 = kt * 64, j0 = jt * 64;

    {   // load: j-row r, 16 k's per thread
        const int r = tid >> 2, q = tid & 3;
        const float* g = &W[(size_t)(j0 + r) * K_DIM + k0 + q * 16];
#pragma unroll
        for (int t = 0; t < 4; t++) {
            float4 f = *(const float4*)(g + 4 * t);
            L[r][q * 16 + 4 * t + 0] = f.x;
            L[r][q * 16 + 4 * t + 1] = f.y;
            L[r][q * 16 + 4 * t + 2] = f.z;
            L[r][q * 16 + 4 * t + 3] = f.w;
        }
    }
    __syncthreads();
    {   // write Wt tile: k-row kk, 16 j's per thread
        const int kk = tid >> 2, q = tid & 3;
        float* o = &Wt[(size_t)(k0 + kk) * N_DIM + j0 + q * 16];
#pragma unroll
        for (int t = 0; t < 4; t++) {
            float4 f = {L[q * 16 + 4 * t + 0][kk], L[q * 16 + 4 * t + 1][kk],
                        L[q * 16 + 4 * t + 2][kk], L[q * 16 + 4 * t + 3][kk]};
            *(float4*)(o + 4 * t) = f;
        }
    }
    {   // per-j partial min/max (4 threads/j), then tile-global reduce
        const int jl = tid & 63, seg = tid >> 6;
        float mx = -3.0e38f, mn = 3.0e38f;
#pragma unroll
        for (int i = 0; i < 16; i++) {
            float v = L[jl][seg * 16 + i];
            mx = fmaxf(mx, v);
            mn = fminf(mn, v);
        }
        smx[seg][jl] = mx;
        smn[seg][jl] = mn;
    }
    __syncthreads();
    if (tid < 64) {
        float mx = fmaxf(fmaxf(smx[0][tid], smx[1][tid]), fmaxf(smx[2][tid], smx[3][tid]));
        float mn = fminf(fminf(smn[0][tid], smn[1][tid]), fminf(smn[2][tid], smn[3][tid]));
#pragma unroll
        for (int off = 32; off > 0; off >>= 1) {
            mx = fmaxf(mx, __shfl_down(mx, off, 64));
            mn = fminf(mn, __shfl_down(mn, off, 64));
        }
        if (tid == 0) {
            const int id = jt * 16 + kt;
            tmax[id] = mx;
            tmin[id] = mn;
        }
    }
}

// ---- K2: D (one wave butterfly), candidates, coalesced emit from Wt rows ----
__global__ __launch_bounds__(256)
void emit_pruned(const float* __restrict__ X, const float* __restrict__ Wt,
                 const float* __restrict__ tmax, const float* __restrict__ tmin,
                 const float* __restrict__ Xmax, float* __restrict__ out) {
    __shared__ float sD;
    __shared__ float sval[CAP];
    __shared__ int sidx[CAP];
    __shared__ int scnt;

    const int tid = threadIdx.x;
    const int b = blockIdx.x;

    // --- D'' = max(W) - min(W) from 256 tile pairs (2 KB), wave-0 butterfly ---
    if (tid < 64) {
        float4 a = ((const float4*)tmax)[tid];
        float4 i = ((const float4*)tmin)[tid];
        float mx = fmaxf(fmaxf(a.x, a.y), fmaxf(a.z, a.w));
        float mn = fminf(fminf(i.x, i.y), fminf(i.z, i.w));
#pragma unroll
        for (int off = 32; off > 0; off >>= 1) {
            mx = fmaxf(mx, __shfl_down(mx, off, 64));
            mn = fminf(mn, __shfl_down(mn, off, 64));
        }
        if (tid == 0) sD = (mx - mn) * 1.0001f + 1e-6f;  // pad vs fp rounding
    }
    if (tid == 0) scnt = 0;
    __syncthreads();
    const float thr = Xmax[b] - sD;

    // --- candidate list ---
    const float4 xv = ((const float4*)X)[b * (K_DIM / 4) + tid];
    const float xa[4] = {xv.x, xv.y, xv.z, xv.w};
#pragma unroll
    for (int c = 0; c < 4; c++) {
        if (xa[c] > thr) {
            int p = atomicAdd(&scnt, 1);
            if (p < CAP) { sidx[p] = tid * 4 + c; sval[p] = xa[c]; }
        }
    }
    __syncthreads();
    const int n = scnt;

    // --- emit: coalesced float4 reads of Wt rows ---
    float4 acc = {-3.0e38f, -3.0e38f, -3.0e38f, -3.0e38f};
    if (n <= CAP) {
        for (int c = 0; c < n; c++) {
            const int k = sidx[c];
            const float xk = sval[c];
            const float4 w = ((const float4*)Wt)[k * (N_DIM / 4) + tid];
            acc.x = fmaxf(acc.x, xk + w.x);
            acc.y = fmaxf(acc.y, xk + w.y);
            acc.z = fmaxf(acc.z, xk + w.z);
            acc.w = fmaxf(acc.w, xk + w.w);
        }
    } else {
        // overflow fallback (prob ~0): exact full scan, still coalesced
        for (int k = 0; k < K_DIM; k++) {
            const float xk = X[(size_t)b * K_DIM + k];
            const float4 w = ((const float4*)Wt)[k * (N_DIM / 4) + tid];
            acc.x = fmaxf(acc.x, xk + w.x);
            acc.y = fmaxf(acc.y, xk + w.y);
            acc.z = fmaxf(acc.z, xk + w.z);
            acc.w = fmaxf(acc.w, xk + w.w);
        }
    }
    ((float4*)out)[b * (N_DIM / 4) + tid] = acc;
}

extern "C" void kernel_launch(void* const* d_in, const int* in_sizes, int n_in,
                              void* d_out, int out_size, void* d_ws, size_t ws_size,
                              hipStream_t stream) {
    const float* X = (const float*)d_in[0];   // [512][1024]
    const float* W = (const float*)d_in[1];   // [1024][1024]
    float* out = (float*)d_out;               // [512][1024]

    char* ws = (char*)d_ws;
    float* Wt   = (float*)(ws + OFF_WT);
    float* tmax = (float*)(ws + OFF_TMAX);
    float* tmin = (float*)(ws + OFF_TMIN);
    float* Xmax = (float*)(ws + OFF_XMAX);

    prep<<<768, 256, 0, stream>>>(W, X, Wt, tmax, tmin, Xmax);
    emit_pruned<<<M_DIM, 256, 0, stream>>>(X, Wt, tmax, tmin, Xmax, out);
}